// Round 3
// baseline (441.786 us; speedup 1.0000x reference)
//
#include <hip/hip_runtime.h>
#include <stdint.h>

// Problem constants (fixed by reference setup_inputs)
constexpr int N    = 8192;
constexpr int D    = 512;
constexpr int KEXT = 8;
constexpr int NCLS = 1000;
#define TAU_INV 14.285714285714285714f   // 1/0.07

constexpr int BM = 128, BN = 128;
constexpr int NB   = N / BM;             // 64 tile-rows
constexpr int NBLK = NB * (NB + 1) / 2;  // 2080 upper-tri tiles

typedef _Float16 half8 __attribute__((ext_vector_type(8)));
typedef _Float16 half4 __attribute__((ext_vector_type(4)));
typedef float    f32x4 __attribute__((ext_vector_type(4)));

// ---------------- fused prep: histogram + f32->f16 convert + zero ----------
// block 0: label histogram + inverse counts; blocks 1..4096: cvt x4 + zeroing
__global__ void prep_k(const float* __restrict__ q, const int* __restrict__ y,
                       _Float16* __restrict__ qh, int* __restrict__ counts,
                       float* __restrict__ invc, float* __restrict__ pos,
                       float* __restrict__ neg) {
    const int b = blockIdx.x, tid = threadIdx.x;
    if (b == 0) {
        __shared__ int h[NCLS];
        for (int i = tid; i < NCLS; i += 256) h[i] = 0;
        __syncthreads();
        for (int i = tid; i < N; i += 256) atomicAdd(&h[y[i]], 1);
        __syncthreads();
        for (int i = tid; i < NCLS; i += 256) {
            int c = h[i];
            counts[i] = c;
            invc[i]   = 1.0f / (float)c;     // classes with count 0 never indexed
        }
        return;
    }
    const int i = (b - 1) * 256 + tid;       // over N*D/4 float4 groups
    float4 v = reinterpret_cast<const float4*>(q)[i];
    half4 o;
    o.x = (_Float16)v.x; o.y = (_Float16)v.y; o.z = (_Float16)v.z; o.w = (_Float16)v.w;
    reinterpret_cast<half4*>(qh)[i] = o;
    if (i < N) { pos[i] = 0.f; neg[i] = 0.f; }
}

// ---------------- fused symmetric GEMM (q @ q^T) + contrastive epilogue ----
// NO LDS staging, NO barriers in the K-loop: both A and B MFMA fragments for
// 16x16x32 f16 are "row of q, contiguous 16B K-chunk at quad*8" — loaded
// directly global->register (dwordx4, immediate K offsets). qh is 8 MB, fully
// L2/L3 resident; 2 waves per block share each row set via L1.
__global__ __launch_bounds__(256, 2) void gemm_k(
        const _Float16* __restrict__ qh,
        const int* __restrict__ y,
        const float* __restrict__ invc,
        float* __restrict__ pos_sum,
        float* __restrict__ neg_sum) {
    __shared__ int   yis[BM];
    __shared__ int   yjs[BN];
    __shared__ float icsA[BM];
    __shared__ float icsB[BN];

    const int tid  = threadIdx.x;
    const int wave = tid >> 6;
    const int lane = tid & 63;
    const int quad = lane >> 4;
    const int l15  = lane & 15;

    // ---- tile index: XCD-contiguous bands (8 XCDs round-robin on blockIdx) ----
    const int t0 = blockIdx.x;
    const int t  = (t0 & 7) * (NBLK / 8) + (t0 >> 3);   // NBLK/8 = 260 exact

    // ---- decode upper-triangular tile (bi <= bj) ----
    int bi = (int)(((float)(2 * NB + 1) -
                    sqrtf((float)((2 * NB + 1) * (2 * NB + 1)) - 8.0f * (float)t)) * 0.5f);
    if (bi < 0) bi = 0;
    if (bi > NB - 1) bi = NB - 1;
    while ((bi + 1) * NB - ((bi + 1) * bi >> 1) <= t) ++bi;
    while (bi * NB - (bi * (bi - 1) >> 1) > t) --bi;
    const int bj = bi + (t - (bi * NB - (bi * (bi - 1) >> 1)));
    const int ibase = bi * BM, jbase = bj * BN;

    if (tid < BM) {
        int yi = y[ibase + tid];
        int yj = y[jbase + tid];
        yis[tid] = yi;  icsA[tid] = invc[yi];
        yjs[tid] = yj;  icsB[tid] = invc[yj];
    }
    __syncthreads();   // only barrier in the kernel

    // wave position within the 128x128 tile (2x2 waves of 64x64)
    const int wr = (wave >> 1) * 64;
    const int wc = (wave & 1) * 64;

    f32x4 acc[4][4];
#pragma unroll
    for (int a = 0; a < 4; a++)
#pragma unroll
        for (int b = 0; b < 4; b++) acc[a][b] = (f32x4)0.0f;

    // per-lane fragment base pointers: row * D + quad*8 (16B aligned)
    const _Float16* pA[4];
    const _Float16* pB[4];
#pragma unroll
    for (int m = 0; m < 4; m++) {
        pA[m] = qh + (size_t)(ibase + wr + m * 16 + l15) * D + quad * 8;
        pB[m] = qh + (size_t)(jbase + wc + m * 16 + l15) * D + quad * 8;
    }

    // K-loop: 16 steps of K=32; offsets fold into load immediates (ks*64 B)
#pragma unroll
    for (int ks = 0; ks < 16; ks++) {
        half8 af[4], bf[4];
#pragma unroll
        for (int mi = 0; mi < 4; mi++)
            af[mi] = *reinterpret_cast<const half8*>(pA[mi] + ks * 32);
#pragma unroll
        for (int mj = 0; mj < 4; mj++)
            bf[mj] = *reinterpret_cast<const half8*>(pB[mj] + ks * 32);
#pragma unroll
        for (int mi = 0; mi < 4; mi++)
#pragma unroll
            for (int mj = 0; mj < 4; mj++)
                acc[mi][mj] = __builtin_amdgcn_mfma_f32_16x16x32_f16(af[mi], bf[mj], acc[mi][mj], 0, 0, 0);
    }

    // ---- epilogue: masked exp + row/col reductions ----
    int   yjv[4];
    float icj[4];
#pragma unroll
    for (int mj = 0; mj < 4; mj++) {
        int jl = wc + mj * 16 + l15;
        yjv[mj] = yjs[jl];
        icj[mj] = icsB[jl];
    }

    if (bi == bj) {
        // diagonal tile: both orders of each pair are in-tile; row-side only
#pragma unroll
        for (int mi = 0; mi < 4; mi++) {
#pragma unroll
            for (int r = 0; r < 4; r++) {
                const int il   = wr + mi * 16 + quad * 4 + r;   // C/D: row = quad*4+reg
                const int irow = ibase + il;
                const int yi   = yis[il];
                float posp = 0.f, negp = 0.f;
#pragma unroll
                for (int mj = 0; mj < 4; mj++) {
                    const int jcol = jbase + wc + mj * 16 + l15; // C/D: col = lane&15
                    float a    = acc[mi][mj][r];
                    float e    = __expf(a * TAU_INV);
                    bool  nz   = (a != 0.0f);                    // faithful masked_fill(x==0,-inf)
                    bool  same = (yi == yjv[mj]);
                    posp += (same && (irow != jcol) && nz) ? e : 0.0f;
                    negp += (!same && nz) ? e * icj[mj] : 0.0f;
                }
#pragma unroll
                for (int off = 1; off < 16; off <<= 1) {
                    posp += __shfl_xor(posp, off);
                    negp += __shfl_xor(negp, off);
                }
                if (l15 == 0) {
                    atomicAdd(&pos_sum[irow], posp);
                    atomicAdd(&neg_sum[irow], negp);
                }
            }
        }
    } else {
        // off-diagonal tile: each element (i,j) serves both (i,j) and (j,i)
        float cp[4] = {0.f, 0.f, 0.f, 0.f};
        float cn[4] = {0.f, 0.f, 0.f, 0.f};
#pragma unroll
        for (int mi = 0; mi < 4; mi++) {
#pragma unroll
            for (int r = 0; r < 4; r++) {
                const int il   = wr + mi * 16 + quad * 4 + r;
                const int irow = ibase + il;
                const int yi   = yis[il];
                const float ici = icsA[il];
                float posp = 0.f, negp = 0.f;
#pragma unroll
                for (int mj = 0; mj < 4; mj++) {
                    float a    = acc[mi][mj][r];
                    float e    = __expf(a * TAU_INV);
                    bool  nz   = (a != 0.0f);
                    bool  same = (yi == yjv[mj]);
                    float pe   = (same && nz) ? e : 0.0f;        // i != j guaranteed (bi<bj)
                    posp   += pe;
                    cp[mj] += pe;
                    negp   += (!same && nz) ? e * icj[mj] : 0.0f;
                    cn[mj] += (!same && nz) ? e * ici : 0.0f;
                }
#pragma unroll
                for (int off = 1; off < 16; off <<= 1) {
                    posp += __shfl_xor(posp, off);
                    negp += __shfl_xor(negp, off);
                }
                if (l15 == 0) {
                    atomicAdd(&pos_sum[irow], posp);
                    atomicAdd(&neg_sum[irow], negp);
                }
            }
        }
        // column-side: reduce across the 4 quads (rows), lanes quad==0 commit
#pragma unroll
        for (int mj = 0; mj < 4; mj++) {
            float a = cp[mj], b = cn[mj];
            a += __shfl_xor(a, 16); a += __shfl_xor(a, 32);
            b += __shfl_xor(b, 16); b += __shfl_xor(b, 32);
            if (quad == 0) {
                const int jcol = jbase + wc + mj * 16 + l15;
                atomicAdd(&pos_sum[jcol], a);
                atomicAdd(&neg_sum[jcol], b);
            }
        }
    }
}

// ---------------- per-row finalize: k_sims (fp32) + log ratio ----------------
__global__ void finalize_k(const float* __restrict__ q, const float* __restrict__ kmat,
                           const int* __restrict__ y, const int* __restrict__ counts,
                           const float* __restrict__ pos_sum, const float* __restrict__ neg_sum,
                           float* __restrict__ loss) {
    const int wave = threadIdx.x >> 6, lane = threadIdx.x & 63;
    const int i = blockIdx.x * 4 + wave;

    float qv[8];
#pragma unroll
    for (int t = 0; t < 8; t++) qv[t] = q[(size_t)i * D + t * 64 + lane];

    float esum = 0.f;
    for (int kk = 0; kk < KEXT; kk++) {
        const float* kr = kmat + ((size_t)i * KEXT + kk) * D;
        float p = 0.f;
#pragma unroll
        for (int t = 0; t < 8; t++) p = fmaf(qv[t], kr[t * 64 + lane], p);
#pragma unroll
        for (int off = 1; off < 64; off <<= 1) p += __shfl_xor(p, off);
        esum += __expf(p * TAU_INV);
    }
    if (lane == 0) {
        float num = logf(esum + pos_sum[i]);
        float den = logf(neg_sum[i]);
        float cnt = (float)(counts[y[i]] - 1 + KEXT);  // same_class_counts, label-only
        loss[i] = -(num - den) / cnt;
    }
}

__global__ void reduce_k(const float* __restrict__ loss, float* __restrict__ out) {
    __shared__ float part[16];
    int tid = threadIdx.x;   // 1024 threads
    float s = 0.f;
    for (int i = tid; i < N; i += 1024) s += loss[i];
#pragma unroll
    for (int off = 1; off < 64; off <<= 1) s += __shfl_xor(s, off);
    if ((tid & 63) == 0) part[tid >> 6] = s;
    __syncthreads();
    if (tid < 16) {
        float v = part[tid];
#pragma unroll
        for (int off = 1; off < 16; off <<= 1) v += __shfl_xor(v, off);
        if (tid == 0) out[0] = v / (float)N;
    }
}

// ---------------- launch ----------------
extern "C" void kernel_launch(void* const* d_in, const int* in_sizes, int n_in,
                              void* d_out, int out_size, void* d_ws, size_t ws_size,
                              hipStream_t stream) {
    const float* q    = (const float*)d_in[0];
    const float* kmat = (const float*)d_in[1];
    const int*   y    = (const int*)d_in[2];
    float* out = (float*)d_out;

    char* ws = (char*)d_ws;
    _Float16* qh   = (_Float16*)ws;                 // 8 MB: N*D f16
    int*   counts  = (int*)  (ws + 8388608);        // 1000 ints
    float* invc    = (float*)(ws + 8392704);        // 1000 floats
    float* pos     = (float*)(ws + 8396800);        // N floats
    float* neg     = (float*)(ws + 8429568);        // N floats
    float* loss    = (float*)(ws + 8462336);        // N floats

    prep_k    <<<1 + (N * D / 4) / 256, 256, 0, stream>>>(q, y, qh, counts, invc, pos, neg);
    gemm_k    <<<NBLK, 256, 0, stream>>>(qh, y, invc, pos, neg);
    finalize_k<<<N / 4, 256, 0, stream>>>(q, kmat, y, counts, pos, neg, loss);
    reduce_k  <<<1, 1024, 0, stream>>>(loss, out);
}

// Round 4
// 364.736 us; speedup vs baseline: 1.2112x; 1.2112x over previous
//
#include <hip/hip_runtime.h>
#include <stdint.h>

// Problem constants (fixed by reference setup_inputs)
constexpr int N    = 8192;
constexpr int D    = 512;
constexpr int KEXT = 8;
constexpr int NCLS = 1000;
#define TAU_INV  14.285714285714285714f   // 1/0.07
#define SQRT_TI  3.7796447300922722f      // sqrt(1/0.07); folded into packed f16

constexpr int BM = 128, BN = 128;
constexpr int NB   = N / BM;             // 64 tile-rows
constexpr int NBLK = NB * (NB + 1) / 2;  // 2080 upper-tri tiles

typedef _Float16 half8 __attribute__((ext_vector_type(8)));
typedef float    f32x4 __attribute__((ext_vector_type(4)));

// ---------------- fused prep: histogram + fragment-packing of q ------------
// qf layout: fragment (t, ks), t in [0,512) 16-row tile, ks in [0,16) 32-col
// K-step, is a contiguous 1KB block; half8 slot (t*16+ks)*64 + lane holds
// q[t*16 + (lane&15)][ks*32 + (lane>>4)*8 .. +8] * SQRT_TI  — the exact
// per-lane A/B operand mapping of mfma_f32_16x16x32_f16 (validated R1-R3).
__global__ void prep_k(const float* __restrict__ q, const int* __restrict__ y,
                       _Float16* __restrict__ qf, int* __restrict__ counts,
                       float* __restrict__ invc, float* __restrict__ pos,
                       float* __restrict__ neg) {
    const int b = blockIdx.x, tid = threadIdx.x;
    if (b == 0) {
        __shared__ int h[NCLS];
        for (int i = tid; i < NCLS; i += 256) h[i] = 0;
        __syncthreads();
        for (int i = tid; i < N; i += 256) atomicAdd(&h[y[i]], 1);
        __syncthreads();
        for (int i = tid; i < NCLS; i += 256) {
            int c = h[i];
            counts[i] = c;
            invc[i]   = 1.0f / (float)c;     // classes with count 0 never indexed
        }
        return;
    }
    const int gid = (b - 1) * 256 + tid;     // over N*64 8-float groups
    const int row = gid >> 6;                // source row of q
    const int cg  = gid & 63;                // 8-float group within the row
    const float4* src = reinterpret_cast<const float4*>(q + (size_t)row * D + cg * 8);
    float4 v0 = src[0], v1 = src[1];         // coalesced: 64 lanes = full row
    half8 o;
    o[0] = (_Float16)(v0.x * SQRT_TI); o[1] = (_Float16)(v0.y * SQRT_TI);
    o[2] = (_Float16)(v0.z * SQRT_TI); o[3] = (_Float16)(v0.w * SQRT_TI);
    o[4] = (_Float16)(v1.x * SQRT_TI); o[5] = (_Float16)(v1.y * SQRT_TI);
    o[6] = (_Float16)(v1.z * SQRT_TI); o[7] = (_Float16)(v1.w * SQRT_TI);
    const int t = row >> 4, l15 = row & 15, ks = cg >> 2, quad = cg & 3;
    reinterpret_cast<half8*>(qf)[(size_t)(t * 16 + ks) * 64 + quad * 16 + l15] = o;
    if (gid < N) { pos[gid] = 0.f; neg[gid] = 0.f; }
}

// ---------------- fused symmetric GEMM (q @ q^T) + contrastive epilogue ----
// Fragment-packed operands: every A/B load is base + lane*16B — one coalesced
// 1KB burst per wave. No LDS staging, no K-loop barriers; the fully-unrolled
// 16-step loop gives the scheduler 128 independent dwordx4 loads to hoist.
__global__ __launch_bounds__(256, 2) void gemm_k(
        const _Float16* __restrict__ qf,
        const int* __restrict__ y,
        const float* __restrict__ invc,
        float* __restrict__ pos_sum,
        float* __restrict__ neg_sum) {
    __shared__ int   yis[BM];
    __shared__ int   yjs[BN];
    __shared__ float icsA[BM];
    __shared__ float icsB[BN];

    const int tid  = threadIdx.x;
    const int wave = tid >> 6;
    const int lane = tid & 63;
    const int quad = lane >> 4;
    const int l15  = lane & 15;

    // ---- tile index: XCD-contiguous bands (8 XCDs round-robin on blockIdx) ----
    const int t0 = blockIdx.x;
    const int t  = (t0 & 7) * (NBLK / 8) + (t0 >> 3);   // NBLK/8 = 260 exact

    // ---- decode upper-triangular tile (bi <= bj) ----
    int bi = (int)(((float)(2 * NB + 1) -
                    sqrtf((float)((2 * NB + 1) * (2 * NB + 1)) - 8.0f * (float)t)) * 0.5f);
    if (bi < 0) bi = 0;
    if (bi > NB - 1) bi = NB - 1;
    while ((bi + 1) * NB - ((bi + 1) * bi >> 1) <= t) ++bi;
    while (bi * NB - (bi * (bi - 1) >> 1) > t) --bi;
    const int bj = bi + (t - (bi * NB - (bi * (bi - 1) >> 1)));
    const int ibase = bi * BM, jbase = bj * BN;

    if (tid < BM) {
        int yi = y[ibase + tid];
        int yj = y[jbase + tid];
        yis[tid] = yi;  icsA[tid] = invc[yi];
        yjs[tid] = yj;  icsB[tid] = invc[yj];
    }
    __syncthreads();   // only barrier in the kernel

    // wave position within the 128x128 tile (2x2 waves of 64x64)
    const int wr = (wave >> 1) * 64;
    const int wc = (wave & 1) * 64;

    f32x4 acc[4][4];
#pragma unroll
    for (int a = 0; a < 4; a++)
#pragma unroll
        for (int b = 0; b < 4; b++) acc[a][b] = (f32x4)0.0f;

    // fragment-block pointers: tile index = base/16 + m; +lane gives this
    // lane's 16B slot; K-step advances by 64 half8 slots (1KB)
    const half8* fb = reinterpret_cast<const half8*>(qf);
    const half8* pA[4];
    const half8* pB[4];
#pragma unroll
    for (int m = 0; m < 4; m++) {
        pA[m] = fb + (size_t)((bi * 8) + (wr >> 4) + m) * 1024 + lane;
        pB[m] = fb + (size_t)((bj * 8) + (wc >> 4) + m) * 1024 + lane;
    }

#pragma unroll
    for (int ks = 0; ks < 16; ks++) {
        half8 af[4], bf[4];
#pragma unroll
        for (int mi = 0; mi < 4; mi++) af[mi] = pA[mi][ks * 64];
#pragma unroll
        for (int mj = 0; mj < 4; mj++) bf[mj] = pB[mj][ks * 64];
#pragma unroll
        for (int mi = 0; mi < 4; mi++)
#pragma unroll
            for (int mj = 0; mj < 4; mj++)
                acc[mi][mj] = __builtin_amdgcn_mfma_f32_16x16x32_f16(af[mi], bf[mj], acc[mi][mj], 0, 0, 0);
    }

    // ---- epilogue: masked exp + row/col reductions ----
    // acc already holds sim/tau thanks to the sqrt(1/tau) folded into qf.
    int   yjv[4];
    float icj[4];
#pragma unroll
    for (int mj = 0; mj < 4; mj++) {
        int jl = wc + mj * 16 + l15;
        yjv[mj] = yjs[jl];
        icj[mj] = icsB[jl];
    }

    if (bi == bj) {
        // diagonal tile: both orders of each pair are in-tile; row-side only
#pragma unroll
        for (int mi = 0; mi < 4; mi++) {
#pragma unroll
            for (int r = 0; r < 4; r++) {
                const int il   = wr + mi * 16 + quad * 4 + r;   // C/D: row = quad*4+reg
                const int irow = ibase + il;
                const int yi   = yis[il];
                float posp = 0.f, negp = 0.f;
#pragma unroll
                for (int mj = 0; mj < 4; mj++) {
                    const int jcol = jbase + wc + mj * 16 + l15; // C/D: col = lane&15
                    float a    = acc[mi][mj][r];
                    float e    = __expf(a);
                    bool  nz   = (a != 0.0f);                    // faithful masked_fill(x==0,-inf)
                    bool  same = (yi == yjv[mj]);
                    posp += (same && (irow != jcol) && nz) ? e : 0.0f;
                    negp += (!same && nz) ? e * icj[mj] : 0.0f;
                }
#pragma unroll
                for (int off = 1; off < 16; off <<= 1) {
                    posp += __shfl_xor(posp, off);
                    negp += __shfl_xor(negp, off);
                }
                if (l15 == 0) {
                    atomicAdd(&pos_sum[irow], posp);
                    atomicAdd(&neg_sum[irow], negp);
                }
            }
        }
    } else {
        // off-diagonal tile: each element (i,j) serves both (i,j) and (j,i)
        float cp[4] = {0.f, 0.f, 0.f, 0.f};
        float cn[4] = {0.f, 0.f, 0.f, 0.f};
#pragma unroll
        for (int mi = 0; mi < 4; mi++) {
#pragma unroll
            for (int r = 0; r < 4; r++) {
                const int il   = wr + mi * 16 + quad * 4 + r;
                const int irow = ibase + il;
                const int yi   = yis[il];
                const float ici = icsA[il];
                float posp = 0.f, negp = 0.f;
#pragma unroll
                for (int mj = 0; mj < 4; mj++) {
                    float a    = acc[mi][mj][r];
                    float e    = __expf(a);
                    bool  nz   = (a != 0.0f);
                    bool  same = (yi == yjv[mj]);
                    float pe   = (same && nz) ? e : 0.0f;        // i != j guaranteed (bi<bj)
                    posp   += pe;
                    cp[mj] += pe;
                    negp   += (!same && nz) ? e * icj[mj] : 0.0f;
                    cn[mj] += (!same && nz) ? e * ici : 0.0f;
                }
#pragma unroll
                for (int off = 1; off < 16; off <<= 1) {
                    posp += __shfl_xor(posp, off);
                    negp += __shfl_xor(negp, off);
                }
                if (l15 == 0) {
                    atomicAdd(&pos_sum[irow], posp);
                    atomicAdd(&neg_sum[irow], negp);
                }
            }
        }
        // column-side: reduce across the 4 quads (rows), lanes quad==0 commit
#pragma unroll
        for (int mj = 0; mj < 4; mj++) {
            float a = cp[mj], b = cn[mj];
            a += __shfl_xor(a, 16); a += __shfl_xor(a, 32);
            b += __shfl_xor(b, 16); b += __shfl_xor(b, 32);
            if (quad == 0) {
                const int jcol = jbase + wc + mj * 16 + l15;
                atomicAdd(&pos_sum[jcol], a);
                atomicAdd(&neg_sum[jcol], b);
            }
        }
    }
}

// ---------------- per-row finalize: k_sims (fp32, float4 loads) ------------
__global__ void finalize_k(const float* __restrict__ q, const float* __restrict__ kmat,
                           const int* __restrict__ y, const int* __restrict__ counts,
                           const float* __restrict__ pos_sum, const float* __restrict__ neg_sum,
                           float* __restrict__ loss) {
    const int wave = threadIdx.x >> 6, lane = threadIdx.x & 63;
    const int i = blockIdx.x * 4 + wave;

    const float4* q4 = reinterpret_cast<const float4*>(q) + (size_t)i * 128;
    const float4* k4 = reinterpret_cast<const float4*>(kmat) + (size_t)i * KEXT * 128;
    float4 qa = q4[lane], qb = q4[lane + 64];

    float esum = 0.f;
    for (int kk = 0; kk < KEXT; kk++) {
        float4 ka = k4[(size_t)kk * 128 + lane];
        float4 kb = k4[(size_t)kk * 128 + lane + 64];
        float p = qa.x * ka.x;
        p = fmaf(qa.y, ka.y, p); p = fmaf(qa.z, ka.z, p); p = fmaf(qa.w, ka.w, p);
        p = fmaf(qb.x, kb.x, p); p = fmaf(qb.y, kb.y, p);
        p = fmaf(qb.z, kb.z, p); p = fmaf(qb.w, kb.w, p);
#pragma unroll
        for (int off = 1; off < 64; off <<= 1) p += __shfl_xor(p, off);
        esum += __expf(p * TAU_INV);
    }
    if (lane == 0) {
        float num = logf(esum + pos_sum[i]);
        float den = logf(neg_sum[i]);
        float cnt = (float)(counts[y[i]] - 1 + KEXT);  // same_class_counts, label-only
        loss[i] = -(num - den) / cnt;
    }
}

__global__ void reduce_k(const float* __restrict__ loss, float* __restrict__ out) {
    __shared__ float part[16];
    int tid = threadIdx.x;   // 1024 threads
    float s = 0.f;
    for (int i = tid; i < N; i += 1024) s += loss[i];
#pragma unroll
    for (int off = 1; off < 64; off <<= 1) s += __shfl_xor(s, off);
    if ((tid & 63) == 0) part[tid >> 6] = s;
    __syncthreads();
    if (tid < 16) {
        float v = part[tid];
#pragma unroll
        for (int off = 1; off < 16; off <<= 1) v += __shfl_xor(v, off);
        if (tid == 0) out[0] = v / (float)N;
    }
}

// ---------------- launch ----------------
extern "C" void kernel_launch(void* const* d_in, const int* in_sizes, int n_in,
                              void* d_out, int out_size, void* d_ws, size_t ws_size,
                              hipStream_t stream) {
    const float* q    = (const float*)d_in[0];
    const float* kmat = (const float*)d_in[1];
    const int*   y    = (const int*)d_in[2];
    float* out = (float*)d_out;

    char* ws = (char*)d_ws;
    _Float16* qf   = (_Float16*)ws;                 // 8 MB: packed fragments
    int*   counts  = (int*)  (ws + 8388608);        // 1000 ints
    float* invc    = (float*)(ws + 8392704);        // 1000 floats
    float* pos     = (float*)(ws + 8396800);        // N floats
    float* neg     = (float*)(ws + 8429568);        // N floats
    float* loss    = (float*)(ws + 8462336);        // N floats

    prep_k    <<<1 + (N * 64) / 256, 256, 0, stream>>>(q, y, qf, counts, invc, pos, neg);
    gemm_k    <<<NBLK, 256, 0, stream>>>(qf, y, invc, pos, neg);
    finalize_k<<<N / 4, 256, 0, stream>>>(q, kmat, y, counts, pos, neg, loss);
    reduce_k  <<<1, 1024, 0, stream>>>(loss, out);
}